// Round 6
// baseline (415.289 us; speedup 1.0000x reference)
//
#include <hip/hip_runtime.h>
#include <hip/hip_bf16.h>

#define HID 256
#define LN_EPS 1e-5f
#define DENOM_EPS 1e-8f

typedef __attribute__((ext_vector_type(8))) short short8;
typedef __attribute__((ext_vector_type(4))) float f32x4;

#define WP1_ELEMS (28 * 256 * 32)   // K=896 packed, pre-scaled by 0.5
#define WP2_ELEMS (24 * 256 * 32)   // K=768 (3 rels x 256)

__device__ inline unsigned bfpk(float x, float y) {
    __hip_bfloat162 h = __float22bfloat162_rn(make_float2(x, y));
    return *reinterpret_cast<unsigned*>(&h);
}

// async global->LDS, 16B per lane; lds base must be wave-uniform (HW adds lane*16)
__device__ inline void gld16(const void* g, void* l) {
    __builtin_amdgcn_global_load_lds(
        (const __attribute__((address_space(1))) void*)g,
        (__attribute__((address_space(3))) void*)l, 16, 0, 0);
}

// Pack weights into fragment-native layout: wp[ks][col][kk] = W[ks*32+kk][col] (*0.5 for wp1)
__global__ __launch_bounds__(256) void kpack(
    const float* __restrict__ wt, const float* __restrict__ wi,
    const float* __restrict__ wrel,
    __hip_bfloat16* __restrict__ wp1, __hip_bfloat16* __restrict__ wp2)
{
    int idx = blockIdx.x * 256 + threadIdx.x;
    if (idx < WP1_ELEMS) {
        int kk = idx & 31, col = (idx >> 5) & 255, ks = idx >> 13;
        int k = ks * 32 + kk;
        float v = (k < 384) ? wt[k * 256 + col] : wi[(k - 384) * 256 + col];
        wp1[idx] = __float2bfloat16(v * 0.5f);
    } else {
        int j = idx - WP1_ELEMS;
        if (j < WP2_ELEMS) {
            int kk = j & 31, col = (j >> 5) & 255, ks = j >> 13;
            int k = ks * 32 + kk;                 // wrel flat [768][256]
            wp2[j] = __float2bfloat16(wrel[k * 256 + col]);
        }
    }
}

// Build per-dst edge chains: next[e] = atomicExch(head[dst], e). head pre-inited to -1.
__global__ __launch_bounds__(256) void kchain(
    const int* __restrict__ edst, int* __restrict__ head, int* __restrict__ nxt, int E)
{
    int e = blockIdx.x * 256 + threadIdx.x;
    if (e < E) nxt[e] = atomicExch(&head[edst[e]], e);
}

// One wave per dst node: walk chain, acc[rel] += w*h0[src], then
// S[d][rel*256+c] = bf16(acc[rel][c] / max(denom[rel], eps)).
__global__ __launch_bounds__(256) void k2_gather(
    const float* __restrict__ h0, const int* __restrict__ esrc,
    const int* __restrict__ etype, const float* __restrict__ ew,
    const int* __restrict__ head, const int* __restrict__ nxt,
    __hip_bfloat16* __restrict__ S, int N)
{
    int gid = blockIdx.x * 256 + threadIdx.x;
    int d = gid >> 6;
    int lane = gid & 63;
    if (d >= N) return;

    f32x4 a0 = {0.f, 0.f, 0.f, 0.f}, a1 = a0, a2 = a0;
    float d0 = 0.f, d1 = 0.f, d2 = 0.f;

    int e = head[d];
    while (e >= 0) {
        int src = esrc[e];
        int ty = etype[e];       // wave-uniform
        float w = ew[e];
        const float4 h = *(const float4*)(h0 + (size_t)src * HID + lane * 4);
        f32x4 hw = {w * h.x, w * h.y, w * h.z, w * h.w};
        if (ty == 0)      { a0 += hw; d0 += w; }
        else if (ty == 1) { a1 += hw; d1 += w; }
        else              { a2 += hw; d2 += w; }
        e = nxt[e];
    }

    float i0 = 1.0f / fmaxf(d0, DENOM_EPS);
    float i1 = 1.0f / fmaxf(d1, DENOM_EPS);
    float i2 = 1.0f / fmaxf(d2, DENOM_EPS);
    __hip_bfloat16* row = S + (size_t)d * 768;
    uint2 p;
    p = make_uint2(bfpk(a0[0] * i0, a0[1] * i0), bfpk(a0[2] * i0, a0[3] * i0));
    *(uint2*)(row + 0   + lane * 4) = p;
    p = make_uint2(bfpk(a1[0] * i1, a1[1] * i1), bfpk(a1[2] * i1, a1[3] * i1));
    *(uint2*)(row + 256 + lane * 4) = p;
    p = make_uint2(bfpk(a2[0] * i2, a2[1] * i2), bfpk(a2[2] * i2, a2[3] * i2));
    *(uint2*)(row + 512 + lane * 4) = p;
}

// MFMA GEMM, block tile 128x256, 8 waves (2x4), wave tile 64x64.
// 2-deep software pipeline: 3 LDS A-buffers, global_load_lds staging issued TWO
// steps ahead, counted s_waitcnt vmcnt(N) (never 0 mid-loop) + raw s_barrier.
// Per iter (per lane): 4 B reg-loads + S gld_lds (S=2 MODE0 f32, S=1 MODE1 bf16),
// fenced by asm memory clobber -> wait vmcnt(4+S) drains exactly stage(ks).
// LDS linear dest + inverse-swizzled global source + swizzled ds_read (rule #21).
template<int MODE>
__global__ __launch_bounds__(512) void kgemm(
    const float* __restrict__ a0, const float* __restrict__ a1,
    const __hip_bfloat16* __restrict__ Sb,
    const __hip_bfloat16* __restrict__ wp,
    const float* h0in, const float* __restrict__ gamma,
    const float* __restrict__ beta, float* out, int N)
{
    constexpr int NSTEPS = MODE ? 24 : 28;
    constexpr int TB = MODE ? 8192 : 16384;          // bytes per LDS A-tile
    __shared__ __align__(16) unsigned char As[3][TB];
    __shared__ float redS[128][4];
    __shared__ float redQ[128][4];

    const int t = threadIdx.x;
    const int lane = t & 63;
    const int w = t >> 6;
    const int wr = w >> 2, wc = w & 3;
    const int m0 = blockIdx.x * 128;

    auto stageA = [&](int ks, int buf) {
        if constexpr (MODE == 0) {
#pragma unroll
            for (int j = 0; j < 2; ++j) {
                int r = 8 * (2 * w + j) + (lane >> 3);    // tile row
                int grow = m0 + r; if (grow >= N) grow = m0;
                int q = (lane & 7) ^ (lane >> 3);         // logical 16B chunk (c_phys ^ (r&7))
                const float* src = (ks < 12)
                    ? (a0 + (size_t)grow * 384 + ks * 32 + q * 4)
                    : (a1 + (size_t)grow * 512 + (ks - 12) * 32 + q * 4);
                gld16(src, As[buf] + (2 * w + j) * 1024);
            }
        } else {
            int r = 16 * w + (lane >> 2);
            int grow = m0 + r; if (grow >= N) grow = m0;
            int q = (lane & 3) ^ ((lane >> 3) & 3);       // c_phys ^ ((r>>1)&3)
            const __hip_bfloat16* src = Sb + (size_t)grow * 768 + ks * 32 + q * 8;
            gld16(src, As[buf] + w * 1024);
        }
    };
    auto loadB = [&](short8* bf, int ks) {
#pragma unroll
        for (int fc = 0; fc < 4; ++fc)
            bf[fc] = *(const short8*)((const short*)wp +
                      (size_t)(ks * 256 + wc * 64 + fc * 16 + (lane & 15)) * 32 + (lane >> 4) * 8);
    };

    f32x4 acc[4][4];
#pragma unroll
    for (int i = 0; i < 4; ++i)
#pragma unroll
        for (int j = 0; j < 4; ++j) acc[i][j] = (f32x4){0.f, 0.f, 0.f, 0.f};

    short8 bfc[4], bfn[4];

    // prologue: stage steps 0,1 into bufs 0,1; B(0) into regs
    stageA(0, 0);
    stageA(1, 1);
    loadB(bfc, 0);

    const int g = lane >> 4;
    for (int ks = 0; ks < NSTEPS; ++ks) {
        // drain through stage(ks); leave stage(ks+1) [+newer B loads] in flight
        if (ks + 1 < NSTEPS) {
            if constexpr (MODE == 0) asm volatile("s_waitcnt vmcnt(6)" ::: "memory");
            else                     asm volatile("s_waitcnt vmcnt(5)" ::: "memory");
        } else {
            asm volatile("s_waitcnt vmcnt(0)" ::: "memory");
        }
        __builtin_amdgcn_s_barrier();       // raw: no compiler-forced vmcnt(0)
        __builtin_amdgcn_sched_barrier(0);

        if (ks + 1 < NSTEPS) loadB(bfn, ks + 1);
        if (ks + 2 < NSTEPS) stageA(ks + 2, (ks + 2) % 3);

        // fragments from buf[ks%3] (swizzled read)
        const unsigned char* Ab = As[ks % 3];
        short8 af[4];
#pragma unroll
        for (int fr = 0; fr < 4; ++fr) {
            int r = wr * 64 + fr * 16 + (lane & 15);
            if constexpr (MODE == 0) {
                const unsigned char* base = Ab + r * 128;
                f32x4 lo = *(const f32x4*)(base + ((2 * g) ^ (r & 7)) * 16);
                f32x4 hi = *(const f32x4*)(base + ((2 * g + 1) ^ (r & 7)) * 16);
                union { short8 s; unsigned u[4]; } cv;
                cv.u[0] = bfpk(lo[0], lo[1]);
                cv.u[1] = bfpk(lo[2], lo[3]);
                cv.u[2] = bfpk(hi[0], hi[1]);
                cv.u[3] = bfpk(hi[2], hi[3]);
                af[fr] = cv.s;
            } else {
                af[fr] = *(const short8*)(Ab + r * 64 + ((g ^ ((r >> 1) & 3))) * 16);
            }
        }
#pragma unroll
        for (int fr = 0; fr < 4; ++fr)
#pragma unroll
            for (int fc = 0; fc < 4; ++fc)
                acc[fr][fc] = __builtin_amdgcn_mfma_f32_16x16x32_bf16(af[fr], bfc[fc], acc[fr][fc], 0, 0, 0);

        if (ks + 1 < NSTEPS) {
#pragma unroll
            for (int fc = 0; fc < 4; ++fc) bfc[fc] = bfn[fc];
        }
    }

    const int rbase = m0 + wr * 64;
    const int cbase = wc * 64;

    if constexpr (MODE == 0) {
#pragma unroll
        for (int fr = 0; fr < 4; ++fr)
#pragma unroll
            for (int reg = 0; reg < 4; ++reg) {
                int grow = rbase + fr * 16 + (lane >> 4) * 4 + reg;
                if (grow >= N) continue;
#pragma unroll
                for (int fc = 0; fc < 4; ++fc) {
                    float vv = acc[fr][fc][reg];
                    if (grow == 0) vv = 0.f;
                    out[(size_t)grow * 256 + cbase + fc * 16 + (lane & 15)] = vv;
                }
            }
    } else {
        // x = acc + h0 (same-thread read-before-write; out aliases h0in)
#pragma unroll
        for (int fr = 0; fr < 4; ++fr)
#pragma unroll
            for (int reg = 0; reg < 4; ++reg) {
                int grow = rbase + fr * 16 + (lane >> 4) * 4 + reg;
                if (grow < N) {
#pragma unroll
                    for (int fc = 0; fc < 4; ++fc)
                        acc[fr][fc][reg] += h0in[(size_t)grow * 256 + cbase + fc * 16 + (lane & 15)];
                }
            }
#pragma unroll
        for (int fr = 0; fr < 4; ++fr)
#pragma unroll
            for (int reg = 0; reg < 4; ++reg) {
                float s = 0.f, q = 0.f;
#pragma unroll
                for (int fc = 0; fc < 4; ++fc) {
                    float vv = acc[fr][fc][reg];
                    s += vv; q += vv * vv;
                }
#pragma unroll
                for (int off = 1; off < 16; off <<= 1) {
                    s += __shfl_xor(s, off, 64);
                    q += __shfl_xor(q, off, 64);
                }
                if ((lane & 15) == 0) {
                    int rl = wr * 64 + fr * 16 + (lane >> 4) * 4 + reg;
                    redS[rl][wc] = s;
                    redQ[rl][wc] = q;
                }
            }
        __syncthreads();
        float g4[4], b4[4];
#pragma unroll
        for (int fc = 0; fc < 4; ++fc) {
            g4[fc] = gamma[cbase + fc * 16 + (lane & 15)];
            b4[fc] = beta[cbase + fc * 16 + (lane & 15)];
        }
#pragma unroll
        for (int fr = 0; fr < 4; ++fr)
#pragma unroll
            for (int reg = 0; reg < 4; ++reg) {
                int rl = wr * 64 + fr * 16 + (lane >> 4) * 4 + reg;
                int grow = m0 + rl;
                if (grow >= N) continue;
                float s = redS[rl][0] + redS[rl][1] + redS[rl][2] + redS[rl][3];
                float q = redQ[rl][0] + redQ[rl][1] + redQ[rl][2] + redQ[rl][3];
                float mu  = s * (1.f / 256.f);
                float var = q * (1.f / 256.f) - mu * mu;
                float rstd = rsqrtf(var + LN_EPS);
#pragma unroll
                for (int fc = 0; fc < 4; ++fc) {
                    float vv = (acc[fr][fc][reg] - mu) * rstd * g4[fc] + b4[fc];
                    if (grow == 0) vv = 0.f;
                    out[(size_t)grow * 256 + cbase + fc * 16 + (lane & 15)] = vv;
                }
            }
    }
}

extern "C" void kernel_launch(void* const* d_in, const int* in_sizes, int n_in,
                              void* d_out, int out_size, void* d_ws, size_t ws_size,
                              hipStream_t stream) {
    const int N = in_sizes[0] / 384;   // 100000
    const int E = in_sizes[7];         // 300000
    const float* ft    = (const float*)d_in[0];
    const float* fi    = (const float*)d_in[1];
    const float* wt    = (const float*)d_in[2];
    const float* wi    = (const float*)d_in[3];
    const float* wrel  = (const float*)d_in[4];
    const float* gamma = (const float*)d_in[5];
    const float* beta  = (const float*)d_in[6];
    const float* ew    = (const float*)d_in[7];
    const int*   eidx  = (const int*)d_in[8];
    const int*   etype = (const int*)d_in[9];
    float* out = (float*)d_out;

    // ws layout: S bf16 [N][768] | head int[N] | next int[E] | wp1 | wp2
    __hip_bfloat16* S = (__hip_bfloat16*)d_ws;
    int* head = (int*)((char*)d_ws + (size_t)N * 768 * 2);
    int* nxt  = head + N;
    __hip_bfloat16* wp1 = (__hip_bfloat16*)(nxt + E);
    __hip_bfloat16* wp2 = wp1 + WP1_ELEMS;

    hipMemsetAsync(head, 0xFF, (size_t)N * sizeof(int), stream);   // head = -1

    kpack<<<(WP1_ELEMS + WP2_ELEMS + 255) / 256, 256, 0, stream>>>(wt, wi, wrel, wp1, wp2);

    kchain<<<(E + 255) / 256, 256, 0, stream>>>(eidx + E, head, nxt, E);

    const int gblocks = (N + 127) / 128;                 // 782
    kgemm<0><<<gblocks, 512, 0, stream>>>(ft, fi, nullptr, wp1, nullptr, nullptr, nullptr, out, N);

    const int wblocks = (N + 3) / 4;                     // 1 wave per node, 4 waves/block
    k2_gather<<<wblocks, 256, 0, stream>>>(out, eidx, etype, ew, head, nxt, S, N);

    kgemm<1><<<gblocks, 512, 0, stream>>>(nullptr, nullptr, S, wp2, out, gamma, beta, out, N);
}

// Round 7
// 337.682 us; speedup vs baseline: 1.2298x; 1.2298x over previous
//
#include <hip/hip_runtime.h>
#include <hip/hip_bf16.h>

#define HID 256
#define LN_EPS 1e-5f
#define DENOM_EPS 1e-8f

typedef __attribute__((ext_vector_type(8))) short short8;
typedef __attribute__((ext_vector_type(4))) float f32x4;

#define WP1_ELEMS (28 * 256 * 32)   // K=896 packed, pre-scaled by 0.5
#define WP2_ELEMS (24 * 256 * 32)   // K=768 (3 rels x 256)

__device__ inline unsigned bfpk(float x, float y) {
    __hip_bfloat162 h = __float22bfloat162_rn(make_float2(x, y));
    return *reinterpret_cast<unsigned*>(&h);
}

// async global->LDS, 16B per lane; lds base must be wave-uniform (HW adds lane*16)
__device__ inline void gld16(const void* g, void* l) {
    __builtin_amdgcn_global_load_lds(
        (const __attribute__((address_space(1))) void*)g,
        (__attribute__((address_space(3))) void*)l, 16, 0, 0);
}

// Pack weights into fragment-native layout: wp[ks][col][kk] = W[ks*32+kk][col] (*0.5 for wp1)
__global__ __launch_bounds__(256) void kpack(
    const float* __restrict__ wt, const float* __restrict__ wi,
    const float* __restrict__ wrel,
    __hip_bfloat16* __restrict__ wp1, __hip_bfloat16* __restrict__ wp2)
{
    int idx = blockIdx.x * 256 + threadIdx.x;
    if (idx < WP1_ELEMS) {
        int kk = idx & 31, col = (idx >> 5) & 255, ks = idx >> 13;
        int k = ks * 32 + kk;
        float v = (k < 384) ? wt[k * 256 + col] : wi[(k - 384) * 256 + col];
        wp1[idx] = __float2bfloat16(v * 0.5f);
    } else {
        int j = idx - WP1_ELEMS;
        if (j < WP2_ELEMS) {
            int kk = j & 31, col = (j >> 5) & 255, ks = j >> 13;
            int k = ks * 32 + kk;                 // wrel flat [768][256]
            wp2[j] = __float2bfloat16(wrel[k * 256 + col]);
        }
    }
}

// Build per-dst edge chains: next[e] = atomicExch(head[dst], e). head pre-inited to -1.
__global__ __launch_bounds__(256) void kchain(
    const int* __restrict__ edst, int* __restrict__ head, int* __restrict__ nxt, int E)
{
    int e = blockIdx.x * 256 + threadIdx.x;
    if (e < E) nxt[e] = atomicExch(&head[edst[e]], e);
}

// One wave per dst node: walk chain, acc[rel] += w*h0[src], then
// S[d][rel*256+c] = bf16(acc[rel][c] / max(denom[rel], eps)).
__global__ __launch_bounds__(256) void k2_gather(
    const float* __restrict__ h0, const int* __restrict__ esrc,
    const int* __restrict__ etype, const float* __restrict__ ew,
    const int* __restrict__ head, const int* __restrict__ nxt,
    __hip_bfloat16* __restrict__ S, int N)
{
    int gid = blockIdx.x * 256 + threadIdx.x;
    int d = gid >> 6;
    int lane = gid & 63;
    if (d >= N) return;

    f32x4 a0 = {0.f, 0.f, 0.f, 0.f}, a1 = a0, a2 = a0;
    float d0 = 0.f, d1 = 0.f, d2 = 0.f;

    int e = head[d];
    while (e >= 0) {
        int src = esrc[e];
        int ty = etype[e];       // wave-uniform
        float w = ew[e];
        const float4 h = *(const float4*)(h0 + (size_t)src * HID + lane * 4);
        f32x4 hw = {w * h.x, w * h.y, w * h.z, w * h.w};
        if (ty == 0)      { a0 += hw; d0 += w; }
        else if (ty == 1) { a1 += hw; d1 += w; }
        else              { a2 += hw; d2 += w; }
        e = nxt[e];
    }

    float i0 = 1.0f / fmaxf(d0, DENOM_EPS);
    float i1 = 1.0f / fmaxf(d1, DENOM_EPS);
    float i2 = 1.0f / fmaxf(d2, DENOM_EPS);
    __hip_bfloat16* row = S + (size_t)d * 768;
    uint2 p;
    p = make_uint2(bfpk(a0[0] * i0, a0[1] * i0), bfpk(a0[2] * i0, a0[3] * i0));
    *(uint2*)(row + 0   + lane * 4) = p;
    p = make_uint2(bfpk(a1[0] * i1, a1[1] * i1), bfpk(a1[2] * i1, a1[3] * i1));
    *(uint2*)(row + 256 + lane * 4) = p;
    p = make_uint2(bfpk(a2[0] * i2, a2[1] * i2), bfpk(a2[2] * i2, a2[3] * i2));
    *(uint2*)(row + 512 + lane * 4) = p;
}

// MFMA GEMM, block tile 64x256, 4 waves (1x4), wave tile 64x64, 256 threads.
// Small blocks -> ~6 resident blocks/CU: latency hidden by BLOCK-level TLP
// (independent blocks at different pipeline phases), not intra-block ILP.
// A staged global->LDS (global_load_lds), 3 buffers (race-free with plain
// __syncthreads: writes to buf[(ks+1)%3] are separated from its previous
// readers by sync(ks-1)). Linear LDS dest + inverse-swizzled global source +
// swizzled ds_read (rule #21).
// MODE 0: out = ft@wp1a + fi@wp1b (0.5 pre-folded), row 0 zeroed. A f32,
//         cvt to bf16 at fragment read. LDS row = 128B (8x16B), swz c^=(r&7).
// MODE 1: out = LN(h0 + Sb@wp2), row 0 zeroed. A bf16 [N][768]. LDS row = 64B
//         (4x16B), swz c^=((r>>1)&3). h0in aliases out.
template<int MODE>
__global__ __launch_bounds__(256, 4) void kgemm(
    const float* __restrict__ a0, const float* __restrict__ a1,
    const __hip_bfloat16* __restrict__ Sb,
    const __hip_bfloat16* __restrict__ wp,
    const float* h0in, const float* __restrict__ gamma,
    const float* __restrict__ beta, float* out, int N)
{
    constexpr int NSTEPS = MODE ? 24 : 28;
    constexpr int TB = MODE ? 4096 : 8192;           // bytes per LDS A-tile (64 rows)
    __shared__ __align__(16) unsigned char As[3][TB];
    __shared__ float redS[MODE ? 64 : 1][4];
    __shared__ float redQ[MODE ? 64 : 1][4];

    const int t = threadIdx.x;
    const int lane = t & 63;
    const int w = t >> 6;            // wave 0..3 = column strip
    const int m0 = blockIdx.x * 64;
    const int g = lane >> 4;

    auto stageA = [&](int ks, int buf) {
        if constexpr (MODE == 0) {
#pragma unroll
            for (int j = 0; j < 2; ++j) {
                int slot = j * 4 + w;                     // 8-row group 0..7
                int r = slot * 8 + (lane >> 3);           // tile row 0..63
                int grow = m0 + r; if (grow >= N) grow = m0;
                int q = (lane & 7) ^ (lane >> 3);         // phys chunk ^ (r&7)
                const float* src = (ks < 12)
                    ? (a0 + (size_t)grow * 384 + ks * 32 + q * 4)
                    : (a1 + (size_t)grow * 512 + (ks - 12) * 32 + q * 4);
                gld16(src, As[buf] + slot * 1024);
            }
        } else {
            int r = w * 16 + (lane >> 2);
            int grow = m0 + r; if (grow >= N) grow = m0;
            int q = (lane & 3) ^ ((lane >> 3) & 3);       // phys chunk ^ ((r>>1)&3)
            const __hip_bfloat16* src = Sb + (size_t)grow * 768 + ks * 32 + q * 8;
            gld16(src, As[buf] + w * 1024);
        }
    };

    f32x4 acc[4][4];
#pragma unroll
    for (int i = 0; i < 4; ++i)
#pragma unroll
        for (int j = 0; j < 4; ++j) acc[i][j] = (f32x4){0.f, 0.f, 0.f, 0.f};

    stageA(0, 0);                    // prologue

    for (int ks = 0; ks < NSTEPS; ++ks) {
        if (ks + 1 < NSTEPS) stageA(ks + 1, (ks + 1) % 3);
        short8 bf[4];
#pragma unroll
        for (int fc = 0; fc < 4; ++fc)
            bf[fc] = *(const short8*)((const short*)wp +
                      (size_t)(ks * 256 + w * 64 + fc * 16 + (lane & 15)) * 32 + g * 8);

        __syncthreads();             // drains stage(ks) [and ks+1 — depth-0, TLP covers]

        const unsigned char* Ab = As[ks % 3];
        short8 af[4];
#pragma unroll
        for (int fr = 0; fr < 4; ++fr) {
            int r = fr * 16 + (lane & 15);
            if constexpr (MODE == 0) {
                const unsigned char* base = Ab + r * 128;
                f32x4 lo = *(const f32x4*)(base + ((2 * g) ^ (r & 7)) * 16);
                f32x4 hi = *(const f32x4*)(base + ((2 * g + 1) ^ (r & 7)) * 16);
                union { short8 s; unsigned u[4]; } cv;
                cv.u[0] = bfpk(lo[0], lo[1]);
                cv.u[1] = bfpk(lo[2], lo[3]);
                cv.u[2] = bfpk(hi[0], hi[1]);
                cv.u[3] = bfpk(hi[2], hi[3]);
                af[fr] = cv.s;
            } else {
                af[fr] = *(const short8*)(Ab + r * 64 + (g ^ ((r >> 1) & 3)) * 16);
            }
        }
#pragma unroll
        for (int fr = 0; fr < 4; ++fr)
#pragma unroll
            for (int fc = 0; fc < 4; ++fc)
                acc[fr][fc] = __builtin_amdgcn_mfma_f32_16x16x32_bf16(af[fr], bf[fc], acc[fr][fc], 0, 0, 0);
    }

    const int cbase = w * 64;

    if constexpr (MODE == 0) {
#pragma unroll
        for (int fr = 0; fr < 4; ++fr)
#pragma unroll
            for (int reg = 0; reg < 4; ++reg) {
                int grow = m0 + fr * 16 + g * 4 + reg;
                if (grow >= N) continue;
#pragma unroll
                for (int fc = 0; fc < 4; ++fc) {
                    float vv = acc[fr][fc][reg];
                    if (grow == 0) vv = 0.f;
                    out[(size_t)grow * 256 + cbase + fc * 16 + (lane & 15)] = vv;
                }
            }
    } else {
        // x = acc + h0 (same-thread read-before-write; out aliases h0in)
#pragma unroll
        for (int fr = 0; fr < 4; ++fr)
#pragma unroll
            for (int reg = 0; reg < 4; ++reg) {
                int grow = m0 + fr * 16 + g * 4 + reg;
                if (grow < N) {
#pragma unroll
                    for (int fc = 0; fc < 4; ++fc)
                        acc[fr][fc][reg] += h0in[(size_t)grow * 256 + cbase + fc * 16 + (lane & 15)];
                }
            }
#pragma unroll
        for (int fr = 0; fr < 4; ++fr)
#pragma unroll
            for (int reg = 0; reg < 4; ++reg) {
                float s = 0.f, q = 0.f;
#pragma unroll
                for (int fc = 0; fc < 4; ++fc) {
                    float vv = acc[fr][fc][reg];
                    s += vv; q += vv * vv;
                }
#pragma unroll
                for (int off = 1; off < 16; off <<= 1) {
                    s += __shfl_xor(s, off, 64);
                    q += __shfl_xor(q, off, 64);
                }
                if ((lane & 15) == 0) {
                    int rl = fr * 16 + g * 4 + reg;
                    redS[rl][w] = s;
                    redQ[rl][w] = q;
                }
            }
        __syncthreads();
        float g4[4], b4[4];
#pragma unroll
        for (int fc = 0; fc < 4; ++fc) {
            g4[fc] = gamma[cbase + fc * 16 + (lane & 15)];
            b4[fc] = beta[cbase + fc * 16 + (lane & 15)];
        }
#pragma unroll
        for (int fr = 0; fr < 4; ++fr)
#pragma unroll
            for (int reg = 0; reg < 4; ++reg) {
                int rl = fr * 16 + g * 4 + reg;
                int grow = m0 + rl;
                if (grow >= N) continue;
                float s = redS[rl][0] + redS[rl][1] + redS[rl][2] + redS[rl][3];
                float q = redQ[rl][0] + redQ[rl][1] + redQ[rl][2] + redQ[rl][3];
                float mu  = s * (1.f / 256.f);
                float var = q * (1.f / 256.f) - mu * mu;
                float rstd = rsqrtf(var + LN_EPS);
#pragma unroll
                for (int fc = 0; fc < 4; ++fc) {
                    float vv = (acc[fr][fc][reg] - mu) * rstd * g4[fc] + b4[fc];
                    if (grow == 0) vv = 0.f;
                    out[(size_t)grow * 256 + cbase + fc * 16 + (lane & 15)] = vv;
                }
            }
    }
}

extern "C" void kernel_launch(void* const* d_in, const int* in_sizes, int n_in,
                              void* d_out, int out_size, void* d_ws, size_t ws_size,
                              hipStream_t stream) {
    const int N = in_sizes[0] / 384;   // 100000
    const int E = in_sizes[7];         // 300000
    const float* ft    = (const float*)d_in[0];
    const float* fi    = (const float*)d_in[1];
    const float* wt    = (const float*)d_in[2];
    const float* wi    = (const float*)d_in[3];
    const float* wrel  = (const float*)d_in[4];
    const float* gamma = (const float*)d_in[5];
    const float* beta  = (const float*)d_in[6];
    const float* ew    = (const float*)d_in[7];
    const int*   eidx  = (const int*)d_in[8];
    const int*   etype = (const int*)d_in[9];
    float* out = (float*)d_out;

    // ws layout: S bf16 [N][768] | head int[N] | next int[E] | wp1 | wp2
    __hip_bfloat16* S = (__hip_bfloat16*)d_ws;
    int* head = (int*)((char*)d_ws + (size_t)N * 768 * 2);
    int* nxt  = head + N;
    __hip_bfloat16* wp1 = (__hip_bfloat16*)(nxt + E);
    __hip_bfloat16* wp2 = wp1 + WP1_ELEMS;

    hipMemsetAsync(head, 0xFF, (size_t)N * sizeof(int), stream);   // head = -1

    kpack<<<(WP1_ELEMS + WP2_ELEMS + 255) / 256, 256, 0, stream>>>(wt, wi, wrel, wp1, wp2);

    kchain<<<(E + 255) / 256, 256, 0, stream>>>(eidx + E, head, nxt, E);

    const int gblocks = (N + 63) / 64;                   // 1563
    kgemm<0><<<gblocks, 256, 0, stream>>>(ft, fi, nullptr, wp1, nullptr, nullptr, nullptr, out, N);

    const int wblocks = (N + 3) / 4;                     // 1 wave per node, 4 waves/block
    k2_gather<<<wblocks, 256, 0, stream>>>(out, eidx, etype, ew, head, nxt, S, N);

    kgemm<1><<<gblocks, 256, 0, stream>>>(nullptr, nullptr, S, wp2, out, gamma, beta, out, N);
}

// Round 8
// 322.980 us; speedup vs baseline: 1.2858x; 1.0455x over previous
//
#include <hip/hip_runtime.h>
#include <hip/hip_bf16.h>

#define HID 256
#define LN_EPS 1e-5f
#define DENOM_EPS 1e-8f

typedef __attribute__((ext_vector_type(8))) short short8;
typedef __attribute__((ext_vector_type(4))) float f32x4;

#define WP1_ELEMS (28 * 256 * 32)   // K=896 packed, pre-scaled by 0.5
#define WP2_ELEMS (24 * 256 * 32)   // K=768 (3 rels x 256)

__device__ inline unsigned bfpk(float x, float y) {
    __hip_bfloat162 h = __float22bfloat162_rn(make_float2(x, y));
    return *reinterpret_cast<unsigned*>(&h);
}

// async global->LDS, 16B per lane; lds base must be wave-uniform (HW adds lane*16)
__device__ inline void gld16(const void* g, void* l) {
    __builtin_amdgcn_global_load_lds(
        (const __attribute__((address_space(1))) void*)g,
        (__attribute__((address_space(3))) void*)l, 16, 0, 0);
}

// Pack weights into fragment-native layout: wp[ks][col][kk] = W[ks*32+kk][col] (*0.5 for wp1)
__global__ __launch_bounds__(256) void kpack(
    const float* __restrict__ wt, const float* __restrict__ wi,
    const float* __restrict__ wrel,
    __hip_bfloat16* __restrict__ wp1, __hip_bfloat16* __restrict__ wp2)
{
    int idx = blockIdx.x * 256 + threadIdx.x;
    if (idx < WP1_ELEMS) {
        int kk = idx & 31, col = (idx >> 5) & 255, ks = idx >> 13;
        int k = ks * 32 + kk;
        float v = (k < 384) ? wt[k * 256 + col] : wi[(k - 384) * 256 + col];
        wp1[idx] = __float2bfloat16(v * 0.5f);
    } else {
        int j = idx - WP1_ELEMS;
        if (j < WP2_ELEMS) {
            int kk = j & 31, col = (j >> 5) & 255, ks = j >> 13;
            int k = ks * 32 + kk;                 // wrel flat [768][256]
            wp2[j] = __float2bfloat16(wrel[k * 256 + col]);
        }
    }
}

// Build per-dst edge chains: next[e] = atomicExch(head[dst], e). head pre-inited to -1.
__global__ __launch_bounds__(256) void kchain(
    const int* __restrict__ edst, int* __restrict__ head, int* __restrict__ nxt, int E)
{
    int e = blockIdx.x * 256 + threadIdx.x;
    if (e < E) nxt[e] = atomicExch(&head[edst[e]], e);
}

// One wave per dst node: walk chain, acc[rel] += w*h0[src], then
// S[d][rel*256+c] = bf16(acc[rel][c] / max(denom[rel], eps)).
__global__ __launch_bounds__(256) void k2_gather(
    const float* __restrict__ h0, const int* __restrict__ esrc,
    const int* __restrict__ etype, const float* __restrict__ ew,
    const int* __restrict__ head, const int* __restrict__ nxt,
    __hip_bfloat16* __restrict__ S, int N)
{
    int gid = blockIdx.x * 256 + threadIdx.x;
    int d = gid >> 6;
    int lane = gid & 63;
    if (d >= N) return;

    f32x4 a0 = {0.f, 0.f, 0.f, 0.f}, a1 = a0, a2 = a0;
    float d0 = 0.f, d1 = 0.f, d2 = 0.f;

    int e = head[d];
    while (e >= 0) {
        int src = esrc[e];
        int ty = etype[e];       // wave-uniform
        float w = ew[e];
        const float4 h = *(const float4*)(h0 + (size_t)src * HID + lane * 4);
        f32x4 hw = {w * h.x, w * h.y, w * h.z, w * h.w};
        if (ty == 0)      { a0 += hw; d0 += w; }
        else if (ty == 1) { a1 += hw; d1 += w; }
        else              { a2 += hw; d2 += w; }
        e = nxt[e];
    }

    float i0 = 1.0f / fmaxf(d0, DENOM_EPS);
    float i1 = 1.0f / fmaxf(d1, DENOM_EPS);
    float i2 = 1.0f / fmaxf(d2, DENOM_EPS);
    __hip_bfloat16* row = S + (size_t)d * 768;
    uint2 p;
    p = make_uint2(bfpk(a0[0] * i0, a0[1] * i0), bfpk(a0[2] * i0, a0[3] * i0));
    *(uint2*)(row + 0   + lane * 4) = p;
    p = make_uint2(bfpk(a1[0] * i1, a1[1] * i1), bfpk(a1[2] * i1, a1[3] * i1));
    *(uint2*)(row + 256 + lane * 4) = p;
    p = make_uint2(bfpk(a2[0] * i2, a2[1] * i2), bfpk(a2[2] * i2, a2[3] * i2));
    *(uint2*)(row + 512 + lane * 4) = p;
}

// MFMA GEMM, block tile 64x256, 4 waves (1x4), wave tile 64x64, 256 threads.
// Counted-vmcnt pipeline (T4): pair-unrolled K-loop, static bf_e/bf_o B-register
// sets (prefetched 1 step ahead, NO copies), A staged 2 steps ahead into 3 LDS
// buffers via global_load_lds. Per half-step: s_waitcnt vmcnt(6|5) drains exactly
// stage(ks) (leaves stage(ks+1)[s] + B(ks)[4] in flight; s=2 MODE0, 1 MODE1),
// then raw s_barrier. Every VMEM op gets >= 1 full step of latency budget.
// WAR: stage(ks+3) -> buf[ks%3]; its readers (compute ks, even half) lgkm-wait
// before MFMA, which precedes the odd-half barrier that precedes the stage. Safe.
// MODE 0: out = ft@wp1a + fi@wp1b (0.5 pre-folded), row 0 zeroed. A f32,
//         cvt to bf16 at fragment read. LDS row = 128B (8x16B), swz c^=(r&7).
// MODE 1: out = LN(h0 + Sb@wp2), row 0 zeroed. A bf16 [N][768]. LDS row = 64B
//         (4x16B), swz c^=((r>>1)&3). h0in aliases out.
template<int MODE>
__global__ __launch_bounds__(256, 4) void kgemm(
    const float* __restrict__ a0, const float* __restrict__ a1,
    const __hip_bfloat16* __restrict__ Sb,
    const __hip_bfloat16* __restrict__ wp,
    const float* h0in, const float* __restrict__ gamma,
    const float* __restrict__ beta, float* out, int N)
{
    constexpr int NSTEPS = MODE ? 24 : 28;
    constexpr int TB = MODE ? 4096 : 8192;           // bytes per LDS A-tile (64 rows)
    __shared__ __align__(16) unsigned char As[3][TB];
    __shared__ float redS[MODE ? 64 : 1][4];
    __shared__ float redQ[MODE ? 64 : 1][4];

    const int t = threadIdx.x;
    const int lane = t & 63;
    const int w = t >> 6;            // wave 0..3 = column strip
    const int m0 = blockIdx.x * 64;
    const int g = lane >> 4;

    auto stageA = [&](int ks, int buf) {
        if constexpr (MODE == 0) {
#pragma unroll
            for (int j = 0; j < 2; ++j) {
                int slot = j * 4 + w;                     // 8-row group 0..7
                int r = slot * 8 + (lane >> 3);           // tile row 0..63
                int grow = m0 + r; if (grow >= N) grow = m0;
                int q = (lane & 7) ^ (lane >> 3);         // phys chunk ^ (r&7)
                const float* src = (ks < 12)
                    ? (a0 + (size_t)grow * 384 + ks * 32 + q * 4)
                    : (a1 + (size_t)grow * 512 + (ks - 12) * 32 + q * 4);
                gld16(src, As[buf] + slot * 1024);
            }
        } else {
            int r = w * 16 + (lane >> 2);
            int grow = m0 + r; if (grow >= N) grow = m0;
            int q = (lane & 3) ^ ((lane >> 3) & 3);       // phys chunk ^ ((r>>1)&3)
            const __hip_bfloat16* src = Sb + (size_t)grow * 768 + ks * 32 + q * 8;
            gld16(src, As[buf] + w * 1024);
        }
    };
    auto loadB = [&](short8 (&bf)[4], int ks) {
#pragma unroll
        for (int fc = 0; fc < 4; ++fc)
            bf[fc] = *(const short8*)((const short*)wp +
                      (size_t)(ks * 256 + w * 64 + fc * 16 + (lane & 15)) * 32 + g * 8);
    };

    f32x4 acc[4][4];
#pragma unroll
    for (int i = 0; i < 4; ++i)
#pragma unroll
        for (int j = 0; j < 4; ++j) acc[i][j] = (f32x4){0.f, 0.f, 0.f, 0.f};

    auto compute = [&](int ks, short8 (&bf)[4]) {
        const unsigned char* Ab = As[ks % 3];
        short8 af[4];
#pragma unroll
        for (int fr = 0; fr < 4; ++fr) {
            int r = fr * 16 + (lane & 15);
            if constexpr (MODE == 0) {
                const unsigned char* base = Ab + r * 128;
                f32x4 lo = *(const f32x4*)(base + ((2 * g) ^ (r & 7)) * 16);
                f32x4 hi = *(const f32x4*)(base + ((2 * g + 1) ^ (r & 7)) * 16);
                union { short8 s; unsigned u[4]; } cv;
                cv.u[0] = bfpk(lo[0], lo[1]);
                cv.u[1] = bfpk(lo[2], lo[3]);
                cv.u[2] = bfpk(hi[0], hi[1]);
                cv.u[3] = bfpk(hi[2], hi[3]);
                af[fr] = cv.s;
            } else {
                af[fr] = *(const short8*)(Ab + r * 64 + (g ^ ((r >> 1) & 3)) * 16);
            }
        }
#pragma unroll
        for (int fr = 0; fr < 4; ++fr)
#pragma unroll
            for (int fc = 0; fc < 4; ++fc)
                acc[fr][fc] = __builtin_amdgcn_mfma_f32_16x16x32_bf16(af[fr], bf[fc], acc[fr][fc], 0, 0, 0);
    };

    short8 bfe[4], bfo[4];

    // prologue: stages 0,1 in flight; B(0) in flight
    stageA(0, 0);
    stageA(1, 1);
    loadB(bfe, 0);

    constexpr int NP = NSTEPS / 2;
    for (int p = 0; p < NP; ++p) {
        const int ks = 2 * p;
        // ---- even half: compute ks with bfe ----
        if constexpr (MODE == 0) asm volatile("s_waitcnt vmcnt(6)" ::: "memory");
        else                     asm volatile("s_waitcnt vmcnt(5)" ::: "memory");
        __builtin_amdgcn_s_barrier();
        if (ks + 2 < NSTEPS) stageA(ks + 2, (ks + 2) % 3);
        loadB(bfo, ks + 1);
        compute(ks, bfe);
        // ---- odd half: compute ks+1 with bfo ----
        if (p == NP - 1)              asm volatile("s_waitcnt vmcnt(0)" ::: "memory");
        else if constexpr (MODE == 0) asm volatile("s_waitcnt vmcnt(6)" ::: "memory");
        else                          asm volatile("s_waitcnt vmcnt(5)" ::: "memory");
        __builtin_amdgcn_s_barrier();
        if (ks + 3 < NSTEPS) stageA(ks + 3, (ks + 3) % 3);
        if (ks + 2 < NSTEPS) loadB(bfe, ks + 2);
        compute(ks + 1, bfo);
    }

    const int cbase = w * 64;

    if constexpr (MODE == 0) {
#pragma unroll
        for (int fr = 0; fr < 4; ++fr)
#pragma unroll
            for (int reg = 0; reg < 4; ++reg) {
                int grow = m0 + fr * 16 + g * 4 + reg;
                if (grow >= N) continue;
#pragma unroll
                for (int fc = 0; fc < 4; ++fc) {
                    float vv = acc[fr][fc][reg];
                    if (grow == 0) vv = 0.f;
                    out[(size_t)grow * 256 + cbase + fc * 16 + (lane & 15)] = vv;
                }
            }
    } else {
        // x = acc + h0 (same-thread read-before-write; out aliases h0in)
#pragma unroll
        for (int fr = 0; fr < 4; ++fr)
#pragma unroll
            for (int reg = 0; reg < 4; ++reg) {
                int grow = m0 + fr * 16 + g * 4 + reg;
                if (grow < N) {
#pragma unroll
                    for (int fc = 0; fc < 4; ++fc)
                        acc[fr][fc][reg] += h0in[(size_t)grow * 256 + cbase + fc * 16 + (lane & 15)];
                }
            }
#pragma unroll
        for (int fr = 0; fr < 4; ++fr)
#pragma unroll
            for (int reg = 0; reg < 4; ++reg) {
                float s = 0.f, q = 0.f;
#pragma unroll
                for (int fc = 0; fc < 4; ++fc) {
                    float vv = acc[fr][fc][reg];
                    s += vv; q += vv * vv;
                }
#pragma unroll
                for (int off = 1; off < 16; off <<= 1) {
                    s += __shfl_xor(s, off, 64);
                    q += __shfl_xor(q, off, 64);
                }
                if ((lane & 15) == 0) {
                    int rl = fr * 16 + g * 4 + reg;
                    redS[rl][w] = s;
                    redQ[rl][w] = q;
                }
            }
        __syncthreads();
        float g4[4], b4[4];
#pragma unroll
        for (int fc = 0; fc < 4; ++fc) {
            g4[fc] = gamma[cbase + fc * 16 + (lane & 15)];
            b4[fc] = beta[cbase + fc * 16 + (lane & 15)];
        }
#pragma unroll
        for (int fr = 0; fr < 4; ++fr)
#pragma unroll
            for (int reg = 0; reg < 4; ++reg) {
                int rl = fr * 16 + g * 4 + reg;
                int grow = m0 + rl;
                if (grow >= N) continue;
                float s = redS[rl][0] + redS[rl][1] + redS[rl][2] + redS[rl][3];
                float q = redQ[rl][0] + redQ[rl][1] + redQ[rl][2] + redQ[rl][3];
                float mu  = s * (1.f / 256.f);
                float var = q * (1.f / 256.f) - mu * mu;
                float rstd = rsqrtf(var + LN_EPS);
#pragma unroll
                for (int fc = 0; fc < 4; ++fc) {
                    float vv = (acc[fr][fc][reg] - mu) * rstd * g4[fc] + b4[fc];
                    if (grow == 0) vv = 0.f;
                    out[(size_t)grow * 256 + cbase + fc * 16 + (lane & 15)] = vv;
                }
            }
    }
}

extern "C" void kernel_launch(void* const* d_in, const int* in_sizes, int n_in,
                              void* d_out, int out_size, void* d_ws, size_t ws_size,
                              hipStream_t stream) {
    const int N = in_sizes[0] / 384;   // 100000
    const int E = in_sizes[7];         // 300000
    const float* ft    = (const float*)d_in[0];
    const float* fi    = (const float*)d_in[1];
    const float* wt    = (const float*)d_in[2];
    const float* wi    = (const float*)d_in[3];
    const float* wrel  = (const float*)d_in[4];
    const float* gamma = (const float*)d_in[5];
    const float* beta  = (const float*)d_in[6];
    const float* ew    = (const float*)d_in[7];
    const int*   eidx  = (const int*)d_in[8];
    const int*   etype = (const int*)d_in[9];
    float* out = (float*)d_out;

    // ws layout: S bf16 [N][768] | head int[N] | next int[E] | wp1 | wp2
    __hip_bfloat16* S = (__hip_bfloat16*)d_ws;
    int* head = (int*)((char*)d_ws + (size_t)N * 768 * 2);
    int* nxt  = head + N;
    __hip_bfloat16* wp1 = (__hip_bfloat16*)(nxt + E);
    __hip_bfloat16* wp2 = wp1 + WP1_ELEMS;

    hipMemsetAsync(head, 0xFF, (size_t)N * sizeof(int), stream);   // head = -1

    kpack<<<(WP1_ELEMS + WP2_ELEMS + 255) / 256, 256, 0, stream>>>(wt, wi, wrel, wp1, wp2);

    kchain<<<(E + 255) / 256, 256, 0, stream>>>(eidx + E, head, nxt, E);

    const int gblocks = (N + 63) / 64;                   // 1563
    kgemm<0><<<gblocks, 256, 0, stream>>>(ft, fi, nullptr, wp1, nullptr, nullptr, nullptr, out, N);

    const int wblocks = (N + 3) / 4;                     // 1 wave per node, 4 waves/block
    k2_gather<<<wblocks, 256, 0, stream>>>(out, eidx, etype, ew, head, nxt, S, N);

    kgemm<1><<<gblocks, 256, 0, stream>>>(nullptr, nullptr, S, wp2, out, gamma, beta, out, N);
}